// Round 3
// baseline (227.570 us; speedup 1.0000x reference)
//
#include <hip/hip_runtime.h>
#include <math.h>

#define NB 4
#define ND 96
#define NN 512
#define NA 256

static constexpr float C_TANH = 2.8853900817779268f; // 2*log2(e)
static constexpr float LOG2E  = 1.4426950408889634f;

__device__ __forceinline__ float fexp2(float x) {
#if __has_builtin(__builtin_amdgcn_exp2f)
  return __builtin_amdgcn_exp2f(x);
#else
  return exp2f(x);
#endif
}
__device__ __forceinline__ float frcp(float x) {
#if __has_builtin(__builtin_amdgcn_rcpf)
  return __builtin_amdgcn_rcpf(x);
#else
  return 1.0f / x;
#endif
}

// --- k_proj: G1[b,n,a] = C*(x.Wg1 + bg), G2[b,n,a] = C*(x.Wg2), xt = x^T.
// Block = (b, 4 n's), thread = a. Reads Wg rows directly (L2-resident).
__global__ __launch_bounds__(256, 4) void k_proj(const float* __restrict__ x,
                                                 const float* __restrict__ Wg1,
                                                 const float* __restrict__ Wg2,
                                                 const float* __restrict__ bg,
                                                 float* __restrict__ G1,
                                                 float* __restrict__ G2,
                                                 float* __restrict__ xt) {
  __shared__ float4 xsh[ND];  // xsh[d] = x[b, d, n0..n0+3]
  const int tid = threadIdx.x;
  const int b = blockIdx.x >> 7;
  const int n0 = (blockIdx.x & 127) * 4;

  for (int idx = tid; idx < ND * 4; idx += 256) {
    int d = idx >> 2, j = idx & 3;
    ((float*)&xsh[d])[j] = x[(size_t)(b * ND + d) * NN + n0 + j];
  }
  __syncthreads();
  if (tid < ND) {
    float4 v = xsh[tid];
    xt[(size_t)(b * NN + n0 + 0) * ND + tid] = v.x;
    xt[(size_t)(b * NN + n0 + 1) * ND + tid] = v.y;
    xt[(size_t)(b * NN + n0 + 2) * ND + tid] = v.z;
    xt[(size_t)(b * NN + n0 + 3) * ND + tid] = v.w;
  }

  const int a = tid;
  const float bgv = bg[a];
  float acc1[4] = {bgv, bgv, bgv, bgv};
  float acc2[4] = {0.f, 0.f, 0.f, 0.f};
  const float4* __restrict__ w1p = (const float4*)(Wg1 + (size_t)a * ND);
  const float4* __restrict__ w2p = (const float4*)(Wg2 + (size_t)a * ND);

#pragma unroll 4
  for (int d4 = 0; d4 < ND / 4; ++d4) {
    float4 w1 = w1p[d4], w2 = w2p[d4];
    float w1c[4] = {w1.x, w1.y, w1.z, w1.w};
    float w2c[4] = {w2.x, w2.y, w2.z, w2.w};
#pragma unroll
    for (int dd = 0; dd < 4; ++dd) {
      float4 xq = xsh[d4 * 4 + dd];
      float xv[4] = {xq.x, xq.y, xq.z, xq.w};
#pragma unroll
      for (int j = 0; j < 4; ++j) {
        acc1[j] = fmaf(w1c[dd], xv[j], acc1[j]);
        acc2[j] = fmaf(w2c[dd], xv[j], acc2[j]);
      }
    }
  }
#pragma unroll
  for (int j = 0; j < 4; ++j) {
    G1[(size_t)(b * NN + n0 + j) * NA + a] = C_TANH * acc1[j];
    G2[(size_t)(b * NN + n0 + j) * NA + a] = C_TANH * acc2[j];
  }
}

// --- k_main: fused pairwise-tanh attention + AV.
// Grid 2048 = b(4) x ngroup(128, 4 n's) x m-quarter(4, 128 m's).
// 256 threads: tid&127 = m-row, tid>>7 = a-half (chunks of 128 a).
// Hot loop: NO LDS, NO barriers -> pure TLP at ~8 blocks/CU.
__global__ __launch_bounds__(256, 8) void k_main(const float* __restrict__ G1,
                                                 const float* __restrict__ G2,
                                                 const float* __restrict__ xt,
                                                 const float* __restrict__ Wa_w,
                                                 const float* __restrict__ Wa_b,
                                                 const float* __restrict__ ba,
                                                 float* __restrict__ out) {
  __shared__ float psum[2048];   // [w][nl][128]; first 640 alias accsh/swsh
  __shared__ float attsh[512];   // [nl][mloc]
  const int tid = threadIdx.x;
  const int bid = blockIdx.x;
  const int q  = bid & 3;
  const int ng = (bid >> 2) & 127;
  const int b  = bid >> 9;
  const int n0 = ng * 4;
  const int mloc = tid & 127;
  const int ah = __builtin_amdgcn_readfirstlane(tid >> 7);  // wave-uniform
  const int m = q * 128 + mloc;

  const float4* __restrict__ W4 = (const float4*)Wa_w;
  const float* __restrict__ g1r0 = G1 + (size_t)(b * NN + n0) * NA;
  const float* __restrict__ g2row = G2 + (size_t)(b * NN + m) * NA;

  float acc[4] = {0.f, 0.f, 0.f, 0.f};
  float sw = 0.f;

#pragma unroll 1
  for (int ci = 0; ci < 4; ++ci) {
    const int c = ah * 4 + ci;
    const float4* __restrict__ g2c4 = (const float4*)(g2row + c * 32);
#pragma unroll
    for (int h = 0; h < 2; ++h) {
      float4 g2r[4];
#pragma unroll
      for (int i = 0; i < 4; ++i) g2r[i] = g2c4[h * 4 + i];
#pragma unroll
      for (int k4 = 0; k4 < 4; ++k4) {
        float g2v[4] = {g2r[k4].x, g2r[k4].y, g2r[k4].z, g2r[k4].w};
        float4 wq = W4[c * 8 + h * 4 + k4];
        float wv[4] = {wq.x, wq.y, wq.z, wq.w};
        sw += (wv[0] + wv[1]) + (wv[2] + wv[3]);
#pragma unroll
        for (int nl = 0; nl < 4; ++nl) {
          float4 g = *(const float4*)(g1r0 + nl * NA + c * 32 + (h * 4 + k4) * 4);
          float g1v[4] = {g.x, g.y, g.z, g.w};
#pragma unroll
          for (int j = 0; j < 4; ++j) {
            float e = fexp2(g1v[j] + g2v[j]);       // exp2(C*(g1+g2+bg))
            acc[nl] = fmaf(wv[j], frcp(1.f + e), acc[nl]);
          }
        }
      }
    }
  }

  // combine a-halves -> att row scores
  float* accsh = psum;          // [4][128]
  float* swsh  = psum + 512;    // [128]
  if (ah == 1) {
#pragma unroll
    for (int nl = 0; nl < 4; ++nl) accsh[nl * 128 + mloc] = acc[nl];
    swsh[mloc] = sw;
  }
  __syncthreads();
  if (ah == 0) {
    float bias = Wa_b[0] + ba[0];
    float swt = sw + swsh[mloc] + bias;
#pragma unroll
    for (int nl = 0; nl < 4; ++nl) {
      float z = swt - 2.f * (acc[nl] + accsh[nl * 128 + mloc]);
      attsh[nl * 128 + mloc] = frcp(1.f + fexp2(-LOG2E * z));  // sigmoid
    }
  }
  __syncthreads();

  // AV over this block's 128 m-rows: wave w -> m in [w*32, w*32+32)
  const int w = tid >> 6;
  const int l = tid & 63;
  float o0[4] = {0.f, 0.f, 0.f, 0.f};
  float o1[4] = {0.f, 0.f, 0.f, 0.f};
  const float* __restrict__ xb = xt + (size_t)(b * NN + q * 128 + w * 32) * ND;
  for (int mi = 0; mi < 32; ++mi) {
    const float* xr = xb + mi * ND;
    float xv0 = xr[l];
    float xv1 = xr[64 + (l & 31)];
#pragma unroll
    for (int nl = 0; nl < 4; ++nl) {
      float av = attsh[nl * 128 + w * 32 + mi];
      o0[nl] = fmaf(av, xv0, o0[nl]);
      o1[nl] = fmaf(av, xv1, o1[nl]);
    }
  }
  __syncthreads();   // accsh/swsh dead; psum region reused
#pragma unroll
  for (int nl = 0; nl < 4; ++nl) {
    psum[(w * 4 + nl) * 128 + l] = o0[nl];
    if (l < 32) psum[(w * 4 + nl) * 128 + 64 + l] = o1[nl];
  }
  __syncthreads();
#pragma unroll
  for (int it = 0; it < 2; ++it) {
    int idx = it * 256 + tid;
    int nl = idx >> 7;
    int d = idx & 127;
    if (d < ND) {
      float s = (psum[(0 + nl) * 128 + d] + psum[(4 + nl) * 128 + d]) +
                (psum[(8 + nl) * 128 + d] + psum[(12 + nl) * 128 + d]);
      atomicAdd(out + (size_t)(b * NN + n0 + nl) * ND + d, s);
    }
  }
}

extern "C" void kernel_launch(void* const* d_in, const int* in_sizes, int n_in,
                              void* d_out, int out_size, void* d_ws, size_t ws_size,
                              hipStream_t stream) {
  const float* x    = (const float*)d_in[0];
  const float* Wg1  = (const float*)d_in[1];
  const float* Wg2  = (const float*)d_in[2];
  const float* bg   = (const float*)d_in[3];
  const float* Wa_w = (const float*)d_in[4];
  const float* Wa_b = (const float*)d_in[5];
  const float* ba   = (const float*)d_in[6];
  float* out = (float*)d_out;

  float* ws  = (float*)d_ws;
  float* G1  = ws;                 // 4*512*256 = 524288 floats
  float* G2  = ws + 524288;        // 524288
  float* xtw = ws + 1048576;       // 4*512*96 = 196608   (total ~5 MB)

  hipMemsetAsync(out, 0, (size_t)out_size * sizeof(float), stream);
  hipLaunchKernelGGL(k_proj, dim3(512), dim3(256), 0, stream,
                     x, Wg1, Wg2, bg, G1, G2, xtw);
  hipLaunchKernelGGL(k_main, dim3(2048), dim3(256), 0, stream,
                     G1, G2, xtw, Wa_w, Wa_b, ba, out);
}